// Round 1
// baseline (227.411 us; speedup 1.0000x reference)
//
#include <hip/hip_runtime.h>
#include <math.h>

#define B 4
#define H 224
#define W 224
#define C 64
#define K 8
#define WC (W*C)        // 14336
#define HWC (H*W*C)     // 3211264

__device__ inline float wave_reduce_min(float v) {
  #pragma unroll
  for (int off = 32; off > 0; off >>= 1)
    v = fminf(v, __shfl_down(v, off, 64));
  return v;
}
__device__ inline float wave_reduce_max(float v) {
  #pragma unroll
  for (int off = 32; off > 0; off >>= 1)
    v = fmaxf(v, __shfl_down(v, off, 64));
  return v;
}

struct FalseT { static constexpr bool value = false; };
struct TrueT  { static constexpr bool value = true; };

// ================= FAST PATH (needs ws_size >= PBYTES + 8KB) =================

// ---- Kernel A: raw column prefix sums + per-column-block min/max partials ----
// One block per (b,w), 256 threads = 4 h-quarters x 64 channels. Reads x ONCE;
// min/max rides along on the register-resident data (replaces k_minmax_part's
// dedicated 51.4 MB pass). P is written UNNORMALIZED; normalization is deferred
// to k_main2 analytically.
__global__ __launch_bounds__(256) void k_vpfx_raw(const float* __restrict__ x,
                                                  float* __restrict__ P,
                                                  float* __restrict__ pmin,
                                                  float* __restrict__ pmax) {
  int bid = blockIdx.x;           // b*W + w
  int b = bid / W, w = bid % W;
  int q = threadIdx.x >> 6, c = threadIdx.x & 63;
  size_t colbase = (size_t)b*HWC + (size_t)w*C + c;
  const int hq = q * 56;
  const float* xp = x + colbase + (size_t)hq * WC;

  float v[56];
  #pragma unroll
  for (int j = 0; j < 56; ++j) v[j] = xp[(size_t)j * WC];

  float sum = 0.f, vmin = v[0], vmax = v[0];
  #pragma unroll
  for (int j = 0; j < 56; ++j) {
    sum += v[j];
    vmin = fminf(vmin, v[j]);
    vmax = fmaxf(vmax, v[j]);
  }

  __shared__ float lds[256];
  __shared__ float smin[4], smax[4];
  lds[threadIdx.x] = sum;
  float wmin = wave_reduce_min(vmin), wmax = wave_reduce_max(vmax);
  if ((threadIdx.x & 63) == 0) { smin[q] = wmin; smax[q] = wmax; }
  __syncthreads();
  if (threadIdx.x == 0) {
    pmin[bid] = fminf(fminf(smin[0], smin[1]), fminf(smin[2], smin[3]));
    pmax[bid] = fmaxf(fmaxf(smax[0], smax[1]), fmaxf(smax[2], smax[3]));
  }

  // Offset = sum of earlier quarters (q is wave-uniform)
  float acc = 0.f;
  for (int qq = 0; qq < q; ++qq) acc += lds[qq*64 + c];

  float* Pp = P + colbase + (size_t)hq * WC;
  #pragma unroll
  for (int j = 0; j < 56; ++j) {
    acc += v[j];
    Pp[(size_t)j * WC] = acc;           // raw prefix, no (.. - cnt*xmin)*inv
  }
}

// ---- Kernel B: fused box-sums + OLS + BN + histogram + sigmoid (raw-P form) --
// Identical schedule to the 99us R3 k_main. Deferred normalization:
//   meas/inv = max(T - nv*nh*xmin, 0) + eps*rng,  alpha = sum c_s*log(.)
// (sum c_s == 0 kills the log(inv) term exactly). Interior w-chunks (6 of 8):
// nh == r, folded into one per-scale constant -> same op count as before, and
// the wr bounds check disappears. Edge chunks compute nh per step.
__global__ __launch_bounds__(128) void k_main2(
    const float* __restrict__ P, const float* __restrict__ x,
    const float* __restrict__ pmin, const float* __restrict__ pmax,
    const float* __restrict__ ols, const float* __restrict__ anchors,
    const float* __restrict__ hwidths, const float* __restrict__ bn_gamma,
    const float* __restrict__ bn_beta, const float* __restrict__ bn_mean,
    const float* __restrict__ bn_var, float* __restrict__ out) {
  int xcd  = blockIdx.x & 7;
  int i    = blockIdx.x >> 3;        // [0,448)
  int rg   = xcd * 112 + (i >> 2);   // global row in [0,896)
  int wave = threadIdx.x >> 6, c = threadIdx.x & 63;
  int chunk = (i & 3) * 2 + wave;    // [0,8)
  int b = rg / H, h = rg % H;
  int w0 = chunk * 28;

  // --- finalize per-sample min/max from 224 partials (L2-hot) ---
  float vmin = INFINITY, vmax = -INFINITY;
  for (int ii = threadIdx.x; ii < W; ii += 128) {
    vmin = fminf(vmin, pmin[b*W + ii]);
    vmax = fmaxf(vmax, pmax[b*W + ii]);
  }
  vmin = wave_reduce_min(vmin);
  vmax = wave_reduce_max(vmax);
  __shared__ float sred[4];
  if ((threadIdx.x & 63) == 0) { sred[wave*2] = vmin; sred[wave*2+1] = vmax; }
  __syncthreads();
  float xmin = fminf(sred[0], sred[2]);
  float xmax = fmaxf(sred[1], sred[3]);
  float rng  = xmax - xmin + 1e-6f;
  float epsp = 1e-6f * rng;          // eps lifted to the unnormalized domain

  const float LN2 = 0.69314718055994530942f;
  float wg0 = ols[0], wg1 = ols[1], wg2 = ols[2], wg3 = ols[3];
  float l0 = LN2, l1 = 2.f*LN2, l2 = 3.f*LN2, l3 = 4.f*LN2;
  float wsum = wg0 + wg1 + wg2 + wg3;
  float lrbar = (wg0*l0 + wg1*l1 + wg2*l2 + wg3*l3) / wsum;
  float d0 = l0-lrbar, d1 = l1-lrbar, d2 = l2-lrbar, d3 = l3-lrbar;
  float den = wg0*d0*d0 + wg1*d1*d1 + wg2*d2*d2 + wg3*d3*d3;
  float c0 = wg0*d0/den, c1 = wg1*d1/den, c2 = wg2*d2/den, c3 = wg3*d3/den;

  float scl  = bn_gamma[c] * rsqrtf(bn_var[c] + 1e-3f);
  float bofs = bn_beta[c] - bn_mean[c] * scl;
  float anc[K], wd[K];
  #pragma unroll
  for (int k = 0; k < K; ++k) { anc[k] = anchors[c*K + k]; wd[k] = hwidths[c*K + k]; }

  const int hiA[4] = {1, 2, 4, 8};
  const int loA[4] = {0, 1, 3, 7};
  const int rA[4]  = {2, 4, 8, 16};
  const float* pt[4]; const float* pb[4]; float fb[4];
  float Anh[4], Kin[4];
  #pragma unroll
  for (int s = 0; s < 4; ++s) {
    int ht = h + hiA[s]; if (ht > H-1) ht = H-1;
    int hb = h - loA[s] - 1;
    int hbc = hb < 0 ? 0 : hb;
    pt[s] = P + (size_t)b*HWC + (size_t)ht*WC + c;
    pb[s] = P + (size_t)b*HWC + (size_t)hbc*WC + c;
    fb[s] = hb < 0 ? 0.f : 1.f;
    int h0 = h - loA[s]; if (h0 < 0) h0 = 0;
    int nv = ht - h0 + 1;              // in-bounds rows of the vertical window
    Anh[s] = -(float)nv * xmin;        // per-column xmin correction factor
    Kin[s] = (float)rA[s] * Anh[s] + epsp;   // interior: nh == r, eps folded
  }

  const float* xrow = x   + (size_t)b*HWC + (size_t)h*WC + c;
  float*       orow = out + (size_t)b*HWC + (size_t)h*WC + c;

  auto tloop = [&](auto EDGEC) {
    constexpr bool EDGE = decltype(EDGEC)::value;
    float ring2[2]   = {0,0};
    float ring4[4]   = {0,0,0,0};
    float ring8[8]   = {0,0,0,0,0,0,0,0};
    float ring16[16] = {0,0,0,0,0,0,0,0,0,0,0,0,0,0,0,0};
    float T0 = 0.f, T1 = 0.f, T2 = 0.f, T3 = 0.f;
    float abuf[8] = {0,0,0,0,0,0,0,0};

    for (int t0 = 0; t0 < 48; t0 += 16) {
      #pragma unroll
      for (int u = 0; u < 16; ++u) {
        int t  = t0 + u;
        int wr = w0 - 7 + t;
        float m0, m1, m2, m3;
        if constexpr (EDGE) {
          m0 = m1 = m2 = m3 = 0.f;
          if (wr >= 0 && wr < W) {
            int off = wr * C;
            m0 = pt[0][off] - fb[0]*pb[0][off];
            m1 = pt[1][off] - fb[1]*pb[1][off];
            m2 = pt[2][off] - fb[2]*pb[2][off];
            m3 = pt[3][off] - fb[3]*pb[3][off];
          }
        } else {
          // interior chunks: wr is always in [0,W) -> no bounds check
          int off = wr * C;
          m0 = pt[0][off] - fb[0]*pb[0][off];
          m1 = pt[1][off] - fb[1]*pb[1][off];
          m2 = pt[2][off] - fb[2]*pb[2][off];
          m3 = pt[3][off] - fb[3]*pb[3][off];
        }
        T0 += m0 - ring2[u&1];  ring2[u&1]  = m0;
        T1 += m1 - ring4[u&3];  ring4[u&3]  = m1;
        T2 += m2 - ring8[u&7];  ring8[u&7]  = m2;
        T3 += m3 - ring16[u];   ring16[u]   = m3;

        float a0, a1, a2, a3;
        if constexpr (EDGE) {
          float nh0 = (float)(min(wr, W-1) - max(wr-1,  0) + 1);
          float nh1 = (float)(min(wr, W-1) - max(wr-3,  0) + 1);
          float nh2 = (float)(min(wr, W-1) - max(wr-7,  0) + 1);
          float nh3 = (float)(min(wr, W-1) - max(wr-15, 0) + 1);
          a0 = fmaxf(fmaf(Anh[0], nh0, T0) + epsp, epsp);
          a1 = fmaxf(fmaf(Anh[1], nh1, T1) + epsp, epsp);
          a2 = fmaxf(fmaf(Anh[2], nh2, T2) + epsp, epsp);
          a3 = fmaxf(fmaf(Anh[3], nh3, T3) + epsp, epsp);
        } else {
          a0 = fmaxf(T0 + Kin[0], epsp);
          a1 = fmaxf(T1 + Kin[1], epsp);
          a2 = fmaxf(T2 + Kin[2], epsp);
          a3 = fmaxf(T3 + Kin[3], epsp);
        }
        abuf[(u+7)&7] += c0 * __logf(a0);
        abuf[(u+6)&7] += c1 * __logf(a1);
        abuf[(u+4)&7] += c2 * __logf(a2);
        abuf[u&7]     += c3 * __logf(a3);

        int ig = w0 - 15 + t;
        if (t >= 15 && ig <= w0 + 27) {
          float alpha = abuf[u&7];
          float a = alpha * scl + bofs;
          float sc = 0.f;
          #pragma unroll
          for (int k = 0; k < K; ++k)
            sc += fmaxf(0.f, 1.f - wd[k]*fabsf(a - anc[k]));
          float sig = 1.f / (1.f + __expf(-sc));
          float xv = __builtin_nontemporal_load(&xrow[ig*C]);
          __builtin_nontemporal_store(xv + sig, &orow[ig*C]);
        }
        abuf[u&7] = 0.f;
      }
    }
  };
  // interior iff every wr in [w0-7, w0+40] has full horizontal windows in-bounds
  if (w0 >= 22 && w0 <= 183) tloop(FalseT{}); else tloop(TrueT{});
}

// ================= FALLBACK PATH (verbatim R3/R4 pipeline) =================

__global__ __launch_bounds__(256) void k_minmax_part(const float* __restrict__ x,
                                                     float* __restrict__ scratch) {
  int s   = blockIdx.x >> 9;
  int blk = blockIdx.x & 511;
  const float4* xs = (const float4*)(x + (size_t)s * HWC);
  const int n4 = HWC / 4;
  float vmin = INFINITY, vmax = -INFINITY;
  for (int i = blk*256 + threadIdx.x; i < n4; i += 512*256) {
    float4 v = xs[i];
    vmin = fminf(vmin, fminf(fminf(v.x, v.y), fminf(v.z, v.w)));
    vmax = fmaxf(vmax, fmaxf(fmaxf(v.x, v.y), fmaxf(v.z, v.w)));
  }
  __shared__ float smin[4], smax[4];
  float wmin = wave_reduce_min(vmin), wmax = wave_reduce_max(vmax);
  int wave = threadIdx.x >> 6, lane = threadIdx.x & 63;
  if (lane == 0) { smin[wave] = wmin; smax[wave] = wmax; }
  __syncthreads();
  if (threadIdx.x == 0) {
    float m = fminf(fminf(smin[0], smin[1]), fminf(smin[2], smin[3]));
    float M = fmaxf(fmaxf(smax[0], smax[1]), fmaxf(smax[2], smax[3]));
    scratch[blockIdx.x]        = m;
    scratch[2048 + blockIdx.x] = M;
  }
}

__global__ __launch_bounds__(256) void k_vpfx(const float* __restrict__ x,
                                              const float* __restrict__ scratch,
                                              float* __restrict__ P) {
  int bid = blockIdx.x;
  int b = bid / W, w = bid % W;
  int q = threadIdx.x >> 6, c = threadIdx.x & 63;

  float vmin = fminf(scratch[b*512 + threadIdx.x], scratch[b*512 + 256 + threadIdx.x] - 0.f);
  float vmax = fmaxf(scratch[2048 + b*512 + threadIdx.x], scratch[2048 + b*512 + 256 + threadIdx.x]);
  __shared__ float smin[4], smax[4];
  float wmin = wave_reduce_min(vmin), wmax = wave_reduce_max(vmax);
  if ((threadIdx.x & 63) == 0) { smin[q] = wmin; smax[q] = wmax; }
  __syncthreads();
  float xmin = fminf(fminf(smin[0], smin[1]), fminf(smin[2], smin[3]));
  float xmax = fmaxf(fmaxf(smax[0], smax[1]), fmaxf(smax[2], smax[3]));
  float inv  = 1.0f / (xmax - xmin + 1e-6f);

  size_t colbase = (size_t)b*HWC + (size_t)w*C + c;
  const int hq = q * 56;
  const float* xp = x + colbase + (size_t)hq * WC;

  float v[56];
  #pragma unroll
  for (int j = 0; j < 56; ++j) v[j] = xp[(size_t)j * WC];
  float sum = 0.f;
  #pragma unroll
  for (int j = 0; j < 56; ++j) sum += v[j];

  __shared__ float lds[256];
  lds[threadIdx.x] = sum;
  __syncthreads();

  float acc = 0.f;
  for (int qq = 0; qq < q; ++qq) acc += lds[qq*64 + c];

  float* Pp = P + colbase + (size_t)hq * WC;
  #pragma unroll
  for (int j = 0; j < 56; ++j) {
    acc += v[j];
    Pp[(size_t)j * WC] = (acc - (float)(hq + j + 1) * xmin) * inv;
  }
}

__global__ __launch_bounds__(128) void k_main(
    const float* __restrict__ P, const float* __restrict__ x,
    const float* __restrict__ ols, const float* __restrict__ anchors,
    const float* __restrict__ hwidths, const float* __restrict__ bn_gamma,
    const float* __restrict__ bn_beta, const float* __restrict__ bn_mean,
    const float* __restrict__ bn_var, float* __restrict__ out) {
  int xcd  = blockIdx.x & 7;
  int i    = blockIdx.x >> 3;
  int rg   = xcd * 112 + (i >> 2);
  int wave = threadIdx.x >> 6, c = threadIdx.x & 63;
  int chunk = (i & 3) * 2 + wave;
  int b = rg / H, h = rg % H;
  int w0 = chunk * 28;

  const float LN2 = 0.69314718055994530942f;
  float wg0 = ols[0], wg1 = ols[1], wg2 = ols[2], wg3 = ols[3];
  float l0 = LN2, l1 = 2.f*LN2, l2 = 3.f*LN2, l3 = 4.f*LN2;
  float wsum = wg0 + wg1 + wg2 + wg3;
  float lrbar = (wg0*l0 + wg1*l1 + wg2*l2 + wg3*l3) / wsum;
  float d0 = l0-lrbar, d1 = l1-lrbar, d2 = l2-lrbar, d3 = l3-lrbar;
  float den = wg0*d0*d0 + wg1*d1*d1 + wg2*d2*d2 + wg3*d3*d3;
  float c0 = wg0*d0/den, c1 = wg1*d1/den, c2 = wg2*d2/den, c3 = wg3*d3/den;

  float scl  = bn_gamma[c] * rsqrtf(bn_var[c] + 1e-3f);
  float bofs = bn_beta[c] - bn_mean[c] * scl;
  float anc[K], wd[K];
  #pragma unroll
  for (int k = 0; k < K; ++k) { anc[k] = anchors[c*K + k]; wd[k] = hwidths[c*K + k]; }

  const int hiA[4] = {1, 2, 4, 8};
  const int loA[4] = {0, 1, 3, 7};
  const float* pt[4]; const float* pb[4]; float fb[4];
  #pragma unroll
  for (int s = 0; s < 4; ++s) {
    int ht = h + hiA[s]; if (ht > H-1) ht = H-1;
    int hb = h - loA[s] - 1;
    int hbc = hb < 0 ? 0 : hb;
    pt[s] = P + (size_t)b*HWC + (size_t)ht*WC + c;
    pb[s] = P + (size_t)b*HWC + (size_t)hbc*WC + c;
    fb[s] = hb < 0 ? 0.f : 1.f;
  }

  const float* xrow = x   + (size_t)b*HWC + (size_t)h*WC + c;
  float*       orow = out + (size_t)b*HWC + (size_t)h*WC + c;

  float ring2[2]   = {0,0};
  float ring4[4]   = {0,0,0,0};
  float ring8[8]   = {0,0,0,0,0,0,0,0};
  float ring16[16] = {0,0,0,0,0,0,0,0,0,0,0,0,0,0,0,0};
  float T0 = 0.f, T1 = 0.f, T2 = 0.f, T3 = 0.f;
  float abuf[8] = {0,0,0,0,0,0,0,0};

  for (int t0 = 0; t0 < 48; t0 += 16) {
    #pragma unroll
    for (int u = 0; u < 16; ++u) {
      int t  = t0 + u;
      int wr = w0 - 7 + t;
      float m0 = 0.f, m1 = 0.f, m2 = 0.f, m3 = 0.f;
      if (wr >= 0 && wr < W) {
        int off = wr * C;
        m0 = pt[0][off] - fb[0]*pb[0][off];
        m1 = pt[1][off] - fb[1]*pb[1][off];
        m2 = pt[2][off] - fb[2]*pb[2][off];
        m3 = pt[3][off] - fb[3]*pb[3][off];
      }
      T0 += m0 - ring2[u&1];  ring2[u&1]  = m0;
      T1 += m1 - ring4[u&3];  ring4[u&3]  = m1;
      T2 += m2 - ring8[u&7];  ring8[u&7]  = m2;
      T3 += m3 - ring16[u];   ring16[u]   = m3;
      abuf[(u+7)&7] += c0 * __logf(fmaxf(T0, 0.f) + 1e-6f);
      abuf[(u+6)&7] += c1 * __logf(fmaxf(T1, 0.f) + 1e-6f);
      abuf[(u+4)&7] += c2 * __logf(fmaxf(T2, 0.f) + 1e-6f);
      abuf[u&7]     += c3 * __logf(fmaxf(T3, 0.f) + 1e-6f);
      int ig = w0 - 15 + t;
      if (t >= 15 && ig <= w0 + 27) {
        float alpha = abuf[u&7];
        float a = alpha * scl + bofs;
        float sc = 0.f;
        #pragma unroll
        for (int k = 0; k < K; ++k)
          sc += fmaxf(0.f, 1.f - wd[k]*fabsf(a - anc[k]));
        float sig = 1.f / (1.f + __expf(-sc));
        float xv = __builtin_nontemporal_load(&xrow[ig*C]);
        __builtin_nontemporal_store(xv + sig, &orow[ig*C]);
      }
      abuf[u&7] = 0.f;
    }
  }
}

// ================================ host ================================

extern "C" void kernel_launch(void* const* d_in, const int* in_sizes, int n_in,
                              void* d_out, int out_size, void* d_ws, size_t ws_size,
                              hipStream_t stream) {
  const float* x        = (const float*)d_in[0];
  const float* ols      = (const float*)d_in[1];
  const float* anchors  = (const float*)d_in[2];
  const float* hwidths  = (const float*)d_in[3];
  const float* bn_gamma = (const float*)d_in[4];
  const float* bn_beta  = (const float*)d_in[5];
  const float* bn_mean  = (const float*)d_in[6];
  const float* bn_var   = (const float*)d_in[7];
  float* out = (float*)d_out;
  float* P   = (float*)d_ws;                      // B*H*W*C floats = 51.4 MB
  const size_t PBYTES = (size_t)B * HWC * sizeof(float);

  if (ws_size >= PBYTES + 8192) {
    // fast path: min/max partials live in the workspace tail (no race with out)
    float* pmn = (float*)((char*)d_ws + PBYTES);  // 896 used, 1024 reserved
    float* pmx = pmn + 1024;
    hipLaunchKernelGGL(k_vpfx_raw, dim3(B*W),   dim3(256), 0, stream, x, P, pmn, pmx);
    hipLaunchKernelGGL(k_main2,    dim3(B*H*4), dim3(128), 0, stream,
                       P, x, pmn, pmx, ols, anchors, hwidths,
                       bn_gamma, bn_beta, bn_mean, bn_var, out);
  } else {
    // fallback: verbatim previous 3-kernel pipeline (scratch in d_out)
    float* scratch = out;
    hipLaunchKernelGGL(k_minmax_part, dim3(2048),  dim3(256), 0, stream, x, scratch);
    hipLaunchKernelGGL(k_vpfx,        dim3(B*W),   dim3(256), 0, stream, x, scratch, P);
    hipLaunchKernelGGL(k_main,        dim3(B*H*4), dim3(128), 0, stream,
                       P, x, ols, anchors, hwidths,
                       bn_gamma, bn_beta, bn_mean, bn_var, out);
  }
}